// Round 2
// baseline (596.323 us; speedup 1.0000x reference)
//
#include <hip/hip_runtime.h>

#define LOG2E 1.4426950408889634f
#define SCALE 0.6830207f   // 2048^(-0.05)

typedef __attribute__((ext_vector_type(8))) short bf16x8;
typedef __attribute__((ext_vector_type(4))) float f32x4;

__device__ __forceinline__ unsigned short f2bf(float f) {
  union { float f; unsigned u; } v; v.f = f;
  unsigned r = v.u + 0x7FFFu + ((v.u >> 16) & 1u);
  return (unsigned short)(r >> 16);
}
__device__ __forceinline__ float bf2f(unsigned short h) {
  union { unsigned u; float f; } v; v.u = ((unsigned)h) << 16; return v.f;
}

// ---- prep: W (3x [2048][128] fp32) -> hi/lo bf16 MFMA B-frag layout ----
// Wf*[kc][nt][lane][j] = W[k = kc*32 + (lane>>4)*8 + j][n = nt*16 + (lane&15)]
__global__ __launch_bounds__(256) void prep_wf(const float* __restrict__ Wq,
    const float* __restrict__ Wk, const float* __restrict__ Wv,
    unsigned short* __restrict__ Wfh, unsigned short* __restrict__ Wfl) {
  int t = blockIdx.x * 256 + threadIdx.x;   // 0..98303
  int lane = t & 63;
  int nt = (t >> 6) % 24;
  int kc = t / (64 * 24);
  int g = lane >> 4, c = lane & 15;
  int n = nt * 16 + c;
  const float* W = (n < 128) ? Wq : ((n < 256) ? Wk : Wv);
  int nn = n & 127;
  __align__(16) unsigned short oh[8], ol[8];
#pragma unroll
  for (int j = 0; j < 8; ++j) {
    int k = kc * 32 + g * 8 + j;
    float w = W[k * 128 + nn];
    unsigned short hi = f2bf(w);
    oh[j] = hi;
    ol[j] = f2bf(w - bf2f(hi));
  }
  *(uint4*)(Wfh + (size_t)t * 8) = *(uint4*)oh;
  *(uint4*)(Wfl + (size_t)t * 8) = *(uint4*)ol;
}

// ---- projection: q,k hi/lo bf16 row-major; v transposed single bf16 ----
__global__ __launch_bounds__(256) void proj(const float* __restrict__ x,
    const unsigned short* __restrict__ Wfh, const unsigned short* __restrict__ Wfl,
    unsigned short* __restrict__ qh, unsigned short* __restrict__ ql,
    unsigned short* __restrict__ kh, unsigned short* __restrict__ kl,
    unsigned short* __restrict__ vTo) {
  __shared__ __align__(16) unsigned short Ash[64 * 40];
  __shared__ __align__(16) unsigned short Asl[64 * 40];
  __shared__ __align__(16) unsigned short Bph[24 * 64 * 8];
  __shared__ __align__(16) unsigned short Bpl[24 * 64 * 8];
  int tid = threadIdx.x;
  int wave = tid >> 6, lane = tid & 63;
  int g = lane >> 4, c = lane & 15;
  int m0 = blockIdx.x * 64;
  int wm = (wave & 1) * 32;
  int wn = (wave >> 1) * 12;
  const f32x4 fz = {0.f, 0.f, 0.f, 0.f};
  f32x4 acc[2][12];
#pragma unroll
  for (int a = 0; a < 2; ++a)
#pragma unroll
    for (int q = 0; q < 12; ++q) acc[a][q] = fz;

  for (int kc = 0; kc < 64; ++kc) {
    __syncthreads();
    // stage A tile hi/lo: 64 rows x 32 k
#pragma unroll
    for (int z = 0; z < 2; ++z) {
      int idx = z * 256 + tid;
      int r = idx >> 3, c4 = idx & 7;
      float4 f = *(const float4*)(x + (size_t)(m0 + r) * 2048 + kc * 32 + c4 * 4);
      __align__(8) unsigned short hh[4], ll[4];
      hh[0] = f2bf(f.x); ll[0] = f2bf(f.x - bf2f(hh[0]));
      hh[1] = f2bf(f.y); ll[1] = f2bf(f.y - bf2f(hh[1]));
      hh[2] = f2bf(f.z); ll[2] = f2bf(f.z - bf2f(hh[2]));
      hh[3] = f2bf(f.w); ll[3] = f2bf(f.w - bf2f(hh[3]));
      *(uint2*)(Ash + r * 40 + c4 * 4) = *(uint2*)hh;
      *(uint2*)(Asl + r * 40 + c4 * 4) = *(uint2*)ll;
    }
    // stage B slabs (already frag layout)
    {
      const uint4* sh = (const uint4*)(Wfh + (size_t)kc * 12288);
      const uint4* sl = (const uint4*)(Wfl + (size_t)kc * 12288);
      uint4* dh = (uint4*)Bph;
      uint4* dl = (uint4*)Bpl;
#pragma unroll
      for (int z = 0; z < 6; ++z) {
        dh[z * 256 + tid] = sh[z * 256 + tid];
        dl[z * 256 + tid] = sl[z * 256 + tid];
      }
    }
    __syncthreads();

    bf16x8 afh[2], afl[2];
#pragma unroll
    for (int mt = 0; mt < 2; ++mt) {
      afh[mt] = *(const bf16x8*)(Ash + (wm + mt * 16 + c) * 40 + g * 8);
      afl[mt] = *(const bf16x8*)(Asl + (wm + mt * 16 + c) * 40 + g * 8);
    }
#pragma unroll
    for (int nt = 0; nt < 12; ++nt) {
      bf16x8 bfh = *(const bf16x8*)(Bph + ((wn + nt) * 64 + lane) * 8);
      bf16x8 bfl = *(const bf16x8*)(Bpl + ((wn + nt) * 64 + lane) * 8);
#pragma unroll
      for (int mt = 0; mt < 2; ++mt) {
        acc[mt][nt] = __builtin_amdgcn_mfma_f32_16x16x32_bf16(afh[mt], bfh, acc[mt][nt], 0, 0, 0);
        acc[mt][nt] = __builtin_amdgcn_mfma_f32_16x16x32_bf16(afh[mt], bfl, acc[mt][nt], 0, 0, 0);
        acc[mt][nt] = __builtin_amdgcn_mfma_f32_16x16x32_bf16(afl[mt], bfh, acc[mt][nt], 0, 0, 0);
      }
    }
  }
  // epilogue: D[row=(lane>>4)*4+i][col=lane&15]
#pragma unroll
  for (int mt = 0; mt < 2; ++mt) {
#pragma unroll
    for (int nt = 0; nt < 12; ++nt) {
      int ntg = wn + nt;
      int n = ntg * 16 + c;
      int mat = n >> 7, col = n & 127;
#pragma unroll
      for (int i = 0; i < 4; ++i) {
        int row = m0 + wm + mt * 16 + g * 4 + i;
        float f = acc[mt][nt][i];
        unsigned short hi = f2bf(f);
        if (mat == 0) {
          qh[(size_t)row * 128 + col] = hi;
          ql[(size_t)row * 128 + col] = f2bf(f - bf2f(hi));
        } else if (mat == 1) {
          kh[(size_t)row * 128 + col] = hi;
          kl[(size_t)row * 128 + col] = f2bf(f - bf2f(hi));
        } else {
          vTo[(size_t)col * 16384 + row] = hi;
        }
      }
    }
  }
}

// ---- flash attention, causal, split-precision QK ----
__global__ __launch_bounds__(256) void attn(const unsigned short* __restrict__ qhg,
    const unsigned short* __restrict__ qlg,
    const unsigned short* __restrict__ khg, const unsigned short* __restrict__ klg,
    const unsigned short* __restrict__ vT, float* __restrict__ out) {
  __shared__ __align__(16) unsigned short Ksh[64 * 136];
  __shared__ __align__(16) unsigned short Ksl[64 * 136];
  __shared__ __align__(16) unsigned short Vt[128 * 72];
  __shared__ __align__(16) unsigned short Ps[4][16 * 72];
  int tid = threadIdx.x;
  int wave = tid >> 6, lane = tid & 63;
  int g = lane >> 4, c = lane & 15;
  int b = blockIdx.x >> 6, qt = blockIdx.x & 63;
  int q0 = qt * 64;
  size_t base = (size_t)b * 4096 * 128;

  bf16x8 qfh[4], qfl[4];
#pragma unroll
  for (int kc = 0; kc < 4; ++kc) {
    size_t off = base + (size_t)(q0 + wave * 16 + c) * 128 + kc * 32 + g * 8;
    qfh[kc] = *(const bf16x8*)(qhg + off);
    qfl[kc] = *(const bf16x8*)(qlg + off);
  }

  const f32x4 fz = {0.f, 0.f, 0.f, 0.f};
  f32x4 o[8];
#pragma unroll
  for (int hh = 0; hh < 8; ++hh) o[hh] = fz;
  float mrow[4] = {-1e30f, -1e30f, -1e30f, -1e30f};
  float lrow[4] = {0.f, 0.f, 0.f, 0.f};

  for (int j = 0; j <= qt; ++j) {
    __syncthreads();
#pragma unroll
    for (int z = 0; z < 4; ++z) {
      int idx = z * 256 + tid;
      int r = idx >> 4, c8 = idx & 15;
      size_t goff = base + (size_t)(j * 64 + r) * 128 + c8 * 8;
      *(uint4*)(Ksh + r * 136 + c8 * 8) = *(const uint4*)(khg + goff);
      *(uint4*)(Ksl + r * 136 + c8 * 8) = *(const uint4*)(klg + goff);
    }
#pragma unroll
    for (int z = 0; z < 4; ++z) {
      int idx = z * 256 + tid;
      int hh = idx >> 3, t8 = idx & 7;
      *(uint4*)(Vt + hh * 72 + t8 * 8) =
          *(const uint4*)(vT + (size_t)hh * 16384 + b * 4096 + j * 64 + t8 * 8);
    }
    __syncthreads();

    f32x4 s[4];
#pragma unroll
    for (int nt = 0; nt < 4; ++nt) s[nt] = fz;
#pragma unroll
    for (int kc = 0; kc < 4; ++kc) {
#pragma unroll
      for (int nt = 0; nt < 4; ++nt) {
        bf16x8 kfh = *(const bf16x8*)(Ksh + (nt * 16 + c) * 136 + kc * 32 + g * 8);
        bf16x8 kfl = *(const bf16x8*)(Ksl + (nt * 16 + c) * 136 + kc * 32 + g * 8);
        s[nt] = __builtin_amdgcn_mfma_f32_16x16x32_bf16(qfh[kc], kfh, s[nt], 0, 0, 0);
        s[nt] = __builtin_amdgcn_mfma_f32_16x16x32_bf16(qfh[kc], kfl, s[nt], 0, 0, 0);
        s[nt] = __builtin_amdgcn_mfma_f32_16x16x32_bf16(qfl[kc], kfh, s[nt], 0, 0, 0);
      }
    }
    float tmax[4] = {-1e30f, -1e30f, -1e30f, -1e30f};
    bool diag = (j == qt);
#pragma unroll
    for (int nt = 0; nt < 4; ++nt)
#pragma unroll
      for (int i = 0; i < 4; ++i) {
        float v = s[nt][i] * SCALE;
        if (diag && (nt * 16 + c) > (wave * 16 + g * 4 + i)) v = -1e30f;
        s[nt][i] = v;
        tmax[i] = fmaxf(tmax[i], v);
      }
#pragma unroll
    for (int i = 0; i < 4; ++i)
#pragma unroll
      for (int d = 1; d < 16; d <<= 1)
        tmax[i] = fmaxf(tmax[i], __shfl_xor(tmax[i], d, 64));
    float mnew[4], alpha[4], rsum[4];
#pragma unroll
    for (int i = 0; i < 4; ++i) {
      mnew[i] = fmaxf(mrow[i], tmax[i]);
      alpha[i] = __builtin_amdgcn_exp2f((mrow[i] - mnew[i]) * LOG2E);
      rsum[i] = 0.f;
    }
    float p[4][4];
#pragma unroll
    for (int nt = 0; nt < 4; ++nt)
#pragma unroll
      for (int i = 0; i < 4; ++i) {
        float e = __builtin_amdgcn_exp2f((s[nt][i] - mnew[i]) * LOG2E);
        p[nt][i] = e;
        rsum[i] += e;
      }
#pragma unroll
    for (int i = 0; i < 4; ++i) {
#pragma unroll
      for (int d = 1; d < 16; d <<= 1)
        rsum[i] += __shfl_xor(rsum[i], d, 64);
      lrow[i] = lrow[i] * alpha[i] + rsum[i];
      mrow[i] = mnew[i];
    }
#pragma unroll
    for (int hh = 0; hh < 8; ++hh)
#pragma unroll
      for (int i = 0; i < 4; ++i) o[hh][i] *= alpha[i];
#pragma unroll
    for (int nt = 0; nt < 4; ++nt)
#pragma unroll
      for (int i = 0; i < 4; ++i)
        Ps[wave][(g * 4 + i) * 72 + nt * 16 + c] = f2bf(p[nt][i]);
#pragma unroll
    for (int kc = 0; kc < 2; ++kc) {
      bf16x8 pf = *(const bf16x8*)(&Ps[wave][0] + c * 72 + kc * 32 + g * 8);
#pragma unroll
      for (int hh = 0; hh < 8; ++hh) {
        bf16x8 vf = *(const bf16x8*)(Vt + (hh * 16 + c) * 72 + kc * 32 + g * 8);
        o[hh] = __builtin_amdgcn_mfma_f32_16x16x32_bf16(pf, vf, o[hh], 0, 0, 0);
      }
    }
  }
  float inv[4];
#pragma unroll
  for (int i = 0; i < 4; ++i) inv[i] = 1.0f / lrow[i];
#pragma unroll
  for (int hh = 0; hh < 8; ++hh)
#pragma unroll
    for (int i = 0; i < 4; ++i) {
      size_t row = (size_t)b * 4096 + q0 + wave * 16 + g * 4 + i;
      out[row * 128 + hh * 16 + c] = o[hh][i] * inv[i];
    }
}

extern "C" void kernel_launch(void* const* d_in, const int* in_sizes, int n_in,
                              void* d_out, int out_size, void* d_ws, size_t ws_size,
                              hipStream_t stream) {
  const float* x  = (const float*)d_in[0];
  const float* Wq = (const float*)d_in[1];
  const float* Wk = (const float*)d_in[2];
  const float* Wv = (const float*)d_in[3];
  const size_t NTOK = (size_t)16384 * 128;
  unsigned short* qh = (unsigned short*)d_ws;
  unsigned short* ql = qh + NTOK;
  unsigned short* kh = ql + NTOK;
  unsigned short* kl = kh + NTOK;
  unsigned short* vT = kl + NTOK;
  unsigned short* Wfh = vT + NTOK;      // 64*24*64*8 = 786432
  unsigned short* Wfl = Wfh + (size_t)786432;
  prep_wf<<<384, 256, 0, stream>>>(Wq, Wk, Wv, Wfh, Wfl);
  proj<<<256, 256, 0, stream>>>(x, Wfh, Wfl, qh, ql, kh, kl, vT);
  attn<<<256, 256, 0, stream>>>(qh, ql, kh, kl, vT, (float*)d_out);
}

// Round 3
// 533.163 us; speedup vs baseline: 1.1185x; 1.1185x over previous
//
#include <hip/hip_runtime.h>

#define LOG2E 1.4426950408889634f
#define SCALE 0.6830207f   // 2048^(-0.05)

typedef __attribute__((ext_vector_type(8))) short bf16x8;
typedef __attribute__((ext_vector_type(4))) float f32x4;

__device__ __forceinline__ unsigned short f2bf(float f) {
  union { float f; unsigned u; } v; v.f = f;
  unsigned r = v.u + 0x7FFFu + ((v.u >> 16) & 1u);
  return (unsigned short)(r >> 16);
}
__device__ __forceinline__ float bf2f(unsigned short h) {
  union { unsigned u; float f; } v; v.u = ((unsigned)h) << 16; return v.f;
}

// ---- prep: W (3x [2048][128] fp32) -> hi/lo bf16 MFMA B-frag layout ----
__global__ __launch_bounds__(256) void prep_wf(const float* __restrict__ Wq,
    const float* __restrict__ Wk, const float* __restrict__ Wv,
    unsigned short* __restrict__ Wfh, unsigned short* __restrict__ Wfl) {
  int t = blockIdx.x * 256 + threadIdx.x;   // 0..98303
  int lane = t & 63;
  int nt = (t >> 6) % 24;
  int kc = t / (64 * 24);
  int g = lane >> 4, c = lane & 15;
  int n = nt * 16 + c;
  const float* W = (n < 128) ? Wq : ((n < 256) ? Wk : Wv);
  int nn = n & 127;
  __align__(16) unsigned short oh[8], ol[8];
#pragma unroll
  for (int j = 0; j < 8; ++j) {
    int k = kc * 32 + g * 8 + j;
    float w = W[k * 128 + nn];
    unsigned short hi = f2bf(w);
    oh[j] = hi;
    ol[j] = f2bf(w - bf2f(hi));
  }
  *(uint4*)(Wfh + (size_t)t * 8) = *(uint4*)oh;
  *(uint4*)(Wfl + (size_t)t * 8) = *(uint4*)ol;
}

// ---- projection: BM=32, 512 blocks; B-frags direct from global ----
__global__ __launch_bounds__(256, 4) void proj(const float* __restrict__ x,
    const unsigned short* __restrict__ Wfh, const unsigned short* __restrict__ Wfl,
    unsigned short* __restrict__ qh, unsigned short* __restrict__ ql,
    unsigned short* __restrict__ kh, unsigned short* __restrict__ kl,
    unsigned short* __restrict__ vTo) {
  __shared__ __align__(16) unsigned short Ash[32 * 40];
  __shared__ __align__(16) unsigned short Asl[32 * 40];
  int tid = threadIdx.x;
  int wave = tid >> 6, lane = tid & 63;
  int g = lane >> 4, c = lane & 15;
  int m0 = blockIdx.x * 32;
  int wn = wave * 6;
  const f32x4 fz = {0.f, 0.f, 0.f, 0.f};
  f32x4 acc[2][6];
#pragma unroll
  for (int a = 0; a < 2; ++a)
#pragma unroll
    for (int q = 0; q < 6; ++q) acc[a][q] = fz;

  int r = tid >> 3, c4 = tid & 7;  // 32 rows x 8 float4-quads
  float4 xr = *(const float4*)(x + (size_t)(m0 + r) * 2048 + c4 * 4);

  for (int kc = 0; kc < 64; ++kc) {
    __syncthreads();
    {
      __align__(8) unsigned short hh[4], ll[4];
      hh[0] = f2bf(xr.x); ll[0] = f2bf(xr.x - bf2f(hh[0]));
      hh[1] = f2bf(xr.y); ll[1] = f2bf(xr.y - bf2f(hh[1]));
      hh[2] = f2bf(xr.z); ll[2] = f2bf(xr.z - bf2f(hh[2]));
      hh[3] = f2bf(xr.w); ll[3] = f2bf(xr.w - bf2f(hh[3]));
      *(uint2*)(Ash + r * 40 + c4 * 4) = *(uint2*)hh;
      *(uint2*)(Asl + r * 40 + c4 * 4) = *(uint2*)ll;
    }
    if (kc + 1 < 64)
      xr = *(const float4*)(x + (size_t)(m0 + r) * 2048 + (kc + 1) * 32 + c4 * 4);
    __syncthreads();

    bf16x8 afh[2], afl[2];
#pragma unroll
    for (int mt = 0; mt < 2; ++mt) {
      afh[mt] = *(const bf16x8*)(Ash + (mt * 16 + c) * 40 + g * 8);
      afl[mt] = *(const bf16x8*)(Asl + (mt * 16 + c) * 40 + g * 8);
    }
#pragma unroll
    for (int nt = 0; nt < 6; ++nt) {
      size_t boff = ((size_t)(kc * 24 + wn + nt) * 64 + lane) * 8;
      bf16x8 bfh = *(const bf16x8*)(Wfh + boff);
      bf16x8 bfl = *(const bf16x8*)(Wfl + boff);
#pragma unroll
      for (int mt = 0; mt < 2; ++mt) {
        acc[mt][nt] = __builtin_amdgcn_mfma_f32_16x16x32_bf16(afh[mt], bfh, acc[mt][nt], 0, 0, 0);
        acc[mt][nt] = __builtin_amdgcn_mfma_f32_16x16x32_bf16(afh[mt], bfl, acc[mt][nt], 0, 0, 0);
        acc[mt][nt] = __builtin_amdgcn_mfma_f32_16x16x32_bf16(afl[mt], bfh, acc[mt][nt], 0, 0, 0);
      }
    }
  }
#pragma unroll
  for (int mt = 0; mt < 2; ++mt) {
#pragma unroll
    for (int nt = 0; nt < 6; ++nt) {
      int n = (wn + nt) * 16 + c;
      int mat = n >> 7, col = n & 127;
#pragma unroll
      for (int i = 0; i < 4; ++i) {
        int row = m0 + mt * 16 + g * 4 + i;
        float f = acc[mt][nt][i];
        unsigned short hi = f2bf(f);
        if (mat == 0) {
          qh[(size_t)row * 128 + col] = hi;
          ql[(size_t)row * 128 + col] = f2bf(f - bf2f(hi));
        } else if (mat == 1) {
          kh[(size_t)row * 128 + col] = hi;
          kl[(size_t)row * 128 + col] = f2bf(f - bf2f(hi));
        } else {
          vTo[(size_t)col * 16384 + row] = hi;
        }
      }
    }
  }
}

// ---- flash attention partials: split-KV (chunks of 16 KV-tiles) ----
// unit u -> (b, qt, ch); writes unnormalized O + (m, l) per row
__global__ __launch_bounds__(256, 2) void attn_part(
    const unsigned short* __restrict__ qhg, const unsigned short* __restrict__ qlg,
    const unsigned short* __restrict__ khg, const unsigned short* __restrict__ klg,
    const unsigned short* __restrict__ vT,
    float* __restrict__ Op, float* __restrict__ Ml) {
  __shared__ __align__(16) unsigned short Ksh[64 * 136];
  __shared__ __align__(16) unsigned short Ksl[64 * 136];
  __shared__ __align__(16) unsigned short Vt[128 * 72];
  __shared__ __align__(16) unsigned short Ps[4][16 * 72];
  int tid = threadIdx.x;
  int wave = tid >> 6, lane = tid & 63;
  int g = lane >> 4, c = lane & 15;
  int u = blockIdx.x;
  int b = u / 160, t = u % 160;
  int qt, ch;
  if (t < 16)      { qt = t;                ch = 0; }
  else if (t < 48) { qt = 16 + (t - 16) / 2; ch = (t - 16) % 2; }
  else if (t < 96) { qt = 32 + (t - 48) / 3; ch = (t - 48) % 3; }
  else             { qt = 48 + (t - 96) / 4; ch = (t - 96) % 4; }
  int q0 = qt * 64;
  int jbeg = ch * 16, jend = min(jbeg + 16, qt + 1);
  size_t base = (size_t)b * 4096 * 128;

  bf16x8 qfh[4], qfl[4];
#pragma unroll
  for (int kc = 0; kc < 4; ++kc) {
    size_t off = base + (size_t)(q0 + wave * 16 + c) * 128 + kc * 32 + g * 8;
    qfh[kc] = *(const bf16x8*)(qhg + off);
    qfl[kc] = *(const bf16x8*)(qlg + off);
  }

  const f32x4 fz = {0.f, 0.f, 0.f, 0.f};
  f32x4 o[8];
#pragma unroll
  for (int hh = 0; hh < 8; ++hh) o[hh] = fz;
  float mrow[4] = {-1e30f, -1e30f, -1e30f, -1e30f};
  float lrow[4] = {0.f, 0.f, 0.f, 0.f};

  // prefetch registers
  int kr = tid >> 4, kc8 = tid & 15;      // K: 16 rows x 16 quads per z
  int vh = tid >> 3, vt8 = tid & 7;       // V: 32 h x 8 quads per z
  uint4 rkh[4], rkl[4], rv[4];
#pragma unroll
  for (int z = 0; z < 4; ++z) {
    size_t goff = base + (size_t)(jbeg * 64 + z * 16 + kr) * 128 + kc8 * 8;
    rkh[z] = *(const uint4*)(khg + goff);
    rkl[z] = *(const uint4*)(klg + goff);
    rv[z] = *(const uint4*)(vT + (size_t)(z * 32 + vh) * 16384 + b * 4096 + jbeg * 64 + vt8 * 8);
  }

  for (int j = jbeg; j < jend; ++j) {
    __syncthreads();
#pragma unroll
    for (int z = 0; z < 4; ++z) {
      *(uint4*)(Ksh + (z * 16 + kr) * 136 + kc8 * 8) = rkh[z];
      *(uint4*)(Ksl + (z * 16 + kr) * 136 + kc8 * 8) = rkl[z];
      *(uint4*)(Vt + (z * 32 + vh) * 72 + vt8 * 8) = rv[z];
    }
    if (j + 1 < jend) {
#pragma unroll
      for (int z = 0; z < 4; ++z) {
        size_t goff = base + (size_t)((j + 1) * 64 + z * 16 + kr) * 128 + kc8 * 8;
        rkh[z] = *(const uint4*)(khg + goff);
        rkl[z] = *(const uint4*)(klg + goff);
        rv[z] = *(const uint4*)(vT + (size_t)(z * 32 + vh) * 16384 + b * 4096 + (j + 1) * 64 + vt8 * 8);
      }
    }
    __syncthreads();

    f32x4 s[4];
#pragma unroll
    for (int nt = 0; nt < 4; ++nt) s[nt] = fz;
#pragma unroll
    for (int kc = 0; kc < 4; ++kc) {
#pragma unroll
      for (int nt = 0; nt < 4; ++nt) {
        bf16x8 kfh = *(const bf16x8*)(Ksh + (nt * 16 + c) * 136 + kc * 32 + g * 8);
        bf16x8 kfl = *(const bf16x8*)(Ksl + (nt * 16 + c) * 136 + kc * 32 + g * 8);
        s[nt] = __builtin_amdgcn_mfma_f32_16x16x32_bf16(qfh[kc], kfh, s[nt], 0, 0, 0);
        s[nt] = __builtin_amdgcn_mfma_f32_16x16x32_bf16(qfh[kc], kfl, s[nt], 0, 0, 0);
        s[nt] = __builtin_amdgcn_mfma_f32_16x16x32_bf16(qfl[kc], kfh, s[nt], 0, 0, 0);
      }
    }
    float tmax[4] = {-1e30f, -1e30f, -1e30f, -1e30f};
    bool diag = (j == qt);
#pragma unroll
    for (int nt = 0; nt < 4; ++nt)
#pragma unroll
      for (int i = 0; i < 4; ++i) {
        float v = s[nt][i] * SCALE;
        if (diag && (nt * 16 + c) > (wave * 16 + g * 4 + i)) v = -1e30f;
        s[nt][i] = v;
        tmax[i] = fmaxf(tmax[i], v);
      }
#pragma unroll
    for (int i = 0; i < 4; ++i)
#pragma unroll
      for (int d = 1; d < 16; d <<= 1)
        tmax[i] = fmaxf(tmax[i], __shfl_xor(tmax[i], d, 64));
    float mnew[4], alpha[4], rsum[4];
#pragma unroll
    for (int i = 0; i < 4; ++i) {
      mnew[i] = fmaxf(mrow[i], tmax[i]);
      alpha[i] = __builtin_amdgcn_exp2f((mrow[i] - mnew[i]) * LOG2E);
      rsum[i] = 0.f;
    }
    float p[4][4];
#pragma unroll
    for (int nt = 0; nt < 4; ++nt)
#pragma unroll
      for (int i = 0; i < 4; ++i) {
        float e = __builtin_amdgcn_exp2f((s[nt][i] - mnew[i]) * LOG2E);
        p[nt][i] = e;
        rsum[i] += e;
      }
#pragma unroll
    for (int i = 0; i < 4; ++i) {
#pragma unroll
      for (int d = 1; d < 16; d <<= 1)
        rsum[i] += __shfl_xor(rsum[i], d, 64);
      lrow[i] = lrow[i] * alpha[i] + rsum[i];
      mrow[i] = mnew[i];
    }
#pragma unroll
    for (int hh = 0; hh < 8; ++hh)
#pragma unroll
      for (int i = 0; i < 4; ++i) o[hh][i] *= alpha[i];
#pragma unroll
    for (int nt = 0; nt < 4; ++nt)
#pragma unroll
      for (int i = 0; i < 4; ++i)
        Ps[wave][(g * 4 + i) * 72 + nt * 16 + c] = f2bf(p[nt][i]);
#pragma unroll
    for (int kc = 0; kc < 2; ++kc) {
      bf16x8 pf = *(const bf16x8*)(&Ps[wave][0] + c * 72 + kc * 32 + g * 8);
#pragma unroll
      for (int hh = 0; hh < 8; ++hh) {
        bf16x8 vf = *(const bf16x8*)(Vt + (hh * 16 + c) * 72 + kc * 32 + g * 8);
        o[hh] = __builtin_amdgcn_mfma_f32_16x16x32_bf16(pf, vf, o[hh], 0, 0, 0);
      }
    }
  }
  // write unnormalized partial O + (m,l)
#pragma unroll
  for (int hh = 0; hh < 8; ++hh)
#pragma unroll
    for (int i = 0; i < 4; ++i) {
      int row = wave * 16 + g * 4 + i;
      Op[(size_t)u * 8192 + row * 128 + hh * 16 + c] = o[hh][i];
    }
  if (c == 0) {
#pragma unroll
    for (int i = 0; i < 4; ++i) {
      int row = wave * 16 + g * 4 + i;
      Ml[(size_t)u * 128 + row * 2]     = mrow[i];
      Ml[(size_t)u * 128 + row * 2 + 1] = lrow[i];
    }
  }
}

// ---- merge partials -> out ----
__global__ __launch_bounds__(256) void attn_merge(const float* __restrict__ Op,
    const float* __restrict__ Ml, float* __restrict__ out) {
  int bq = blockIdx.x;
  int b = bq >> 6, qt = bq & 63;
  int nch = qt / 16 + 1;
  int bb = (qt < 16) ? qt : (qt < 32) ? 16 + 2 * (qt - 16)
           : (qt < 48) ? 48 + 3 * (qt - 32) : 96 + 4 * (qt - 48);
  int u0 = b * 160 + bb;
  __shared__ float w[4][64];
  int tid = threadIdx.x;
  if (tid < 64) {
    float m[4], l[4];
    float M = -1e30f;
    for (int uu = 0; uu < nch; ++uu) {
      m[uu] = Ml[(size_t)(u0 + uu) * 128 + tid * 2];
      l[uu] = Ml[(size_t)(u0 + uu) * 128 + tid * 2 + 1];
      M = fmaxf(M, m[uu]);
    }
    float L = 0.f;
    for (int uu = 0; uu < nch; ++uu) {
      float e = __builtin_amdgcn_exp2f((m[uu] - M) * LOG2E);
      w[uu][tid] = e;
      L += l[uu] * e;
    }
    float iL = 1.0f / L;
    for (int uu = 0; uu < nch; ++uu) w[uu][tid] *= iL;
  }
  __syncthreads();
  for (int it = 0; it < 32; ++it) {
    int idx = it * 256 + tid;
    int row = idx >> 7;
    float acc = 0.f;
    for (int uu = 0; uu < nch; ++uu)
      acc += w[uu][row] * Op[(size_t)(u0 + uu) * 8192 + idx];
    out[(size_t)b * 4096 * 128 + (size_t)qt * 8192 + idx] = acc;
  }
}

extern "C" void kernel_launch(void* const* d_in, const int* in_sizes, int n_in,
                              void* d_out, int out_size, void* d_ws, size_t ws_size,
                              hipStream_t stream) {
  const float* x  = (const float*)d_in[0];
  const float* Wq = (const float*)d_in[1];
  const float* Wk = (const float*)d_in[2];
  const float* Wv = (const float*)d_in[3];
  const size_t NTOK = (size_t)16384 * 128;
  unsigned short* qh = (unsigned short*)d_ws;
  unsigned short* ql = qh + NTOK;
  unsigned short* kh = ql + NTOK;
  unsigned short* kl = kh + NTOK;
  unsigned short* vT = kl + NTOK;
  unsigned short* Wfh = vT + NTOK;              // 786432 elems
  unsigned short* Wfl = Wfh + (size_t)786432;
  float* Op = (float*)(Wfl + (size_t)786432);   // 640 * 8192 floats
  float* Ml = Op + (size_t)640 * 8192;          // 640 * 128 floats
  prep_wf<<<384, 256, 0, stream>>>(Wq, Wk, Wv, Wfh, Wfl);
  proj<<<512, 256, 0, stream>>>(x, Wfh, Wfl, qh, ql, kh, kl, vT);
  attn_part<<<640, 256, 0, stream>>>(qh, ql, kh, kl, vT, Op, Ml);
  attn_merge<<<256, 256, 0, stream>>>(Op, Ml, (float*)d_out);
}

// Round 4
// 442.465 us; speedup vs baseline: 1.3477x; 1.2050x over previous
//
#include <hip/hip_runtime.h>

#define LOG2E 1.4426950408889634f
#define SCALE 0.6830207f   // 2048^(-0.05)

typedef __attribute__((ext_vector_type(8))) _Float16 f16x8;
typedef __attribute__((ext_vector_type(4))) _Float16 f16x4;
typedef __attribute__((ext_vector_type(4))) float f32x4;

// ---- prep: W (3x [2048][128] fp32) -> fp16 MFMA B-frag layout ----
// Wf[kc][nt][lane][j] = W[k = kc*32 + (lane>>4)*8 + j][n = nt*16 + (lane&15)]
__global__ __launch_bounds__(256) void prep_wf(const float* __restrict__ Wq,
    const float* __restrict__ Wk, const float* __restrict__ Wv,
    _Float16* __restrict__ Wf) {
  int t = blockIdx.x * 256 + threadIdx.x;   // 0..98303
  int lane = t & 63;
  int nt = (t >> 6) % 24;
  int kc = t / (64 * 24);
  int g = lane >> 4, c = lane & 15;
  int n = nt * 16 + c;
  const float* W = (n < 128) ? Wq : ((n < 256) ? Wk : Wv);
  int nn = n & 127;
  f16x8 o;
#pragma unroll
  for (int j = 0; j < 8; ++j) {
    int k = kc * 32 + g * 8 + j;
    o[j] = (_Float16)W[k * 128 + nn];
  }
  *(f16x8*)(Wf + (size_t)t * 8) = o;
}

// ---- projection: BM=32, BK=64, fp16; B-frags direct from global/L2 ----
__global__ __launch_bounds__(256, 4) void proj(const float* __restrict__ x,
    const _Float16* __restrict__ Wf,
    _Float16* __restrict__ qo, _Float16* __restrict__ ko,
    _Float16* __restrict__ vTo) {
  __shared__ __align__(16) _Float16 As[32 * 72];   // [m][k0..63] pad 72
  int tid = threadIdx.x;
  int wave = tid >> 6, lane = tid & 63;
  int g = lane >> 4, c = lane & 15;
  int m0 = blockIdx.x * 32;
  int wn = wave * 6;
  const f32x4 fz = {0.f, 0.f, 0.f, 0.f};
  f32x4 acc[2][6];
#pragma unroll
  for (int a = 0; a < 2; ++a)
#pragma unroll
    for (int q = 0; q < 6; ++q) acc[a][q] = fz;

  int r = tid >> 3, c4 = tid & 7;  // 32 rows x 8 chunks of 8 floats
  float4 xa = *(const float4*)(x + (size_t)(m0 + r) * 2048 + c4 * 8);
  float4 xb = *(const float4*)(x + (size_t)(m0 + r) * 2048 + c4 * 8 + 4);

  for (int kb = 0; kb < 32; ++kb) {
    __syncthreads();
    {
      f16x8 h8;
      h8[0] = (_Float16)xa.x; h8[1] = (_Float16)xa.y;
      h8[2] = (_Float16)xa.z; h8[3] = (_Float16)xa.w;
      h8[4] = (_Float16)xb.x; h8[5] = (_Float16)xb.y;
      h8[6] = (_Float16)xb.z; h8[7] = (_Float16)xb.w;
      *(f16x8*)(As + r * 72 + c4 * 8) = h8;
    }
    if (kb + 1 < 32) {
      xa = *(const float4*)(x + (size_t)(m0 + r) * 2048 + (kb + 1) * 64 + c4 * 8);
      xb = *(const float4*)(x + (size_t)(m0 + r) * 2048 + (kb + 1) * 64 + c4 * 8 + 4);
    }
    __syncthreads();

#pragma unroll
    for (int kcl = 0; kcl < 2; ++kcl) {
      f16x8 af[2];
#pragma unroll
      for (int mt = 0; mt < 2; ++mt)
        af[mt] = *(const f16x8*)(As + (mt * 16 + c) * 72 + kcl * 32 + g * 8);
#pragma unroll
      for (int nt = 0; nt < 6; ++nt) {
        size_t boff = ((size_t)((kb * 2 + kcl) * 24 + wn + nt) * 64 + lane) * 8;
        f16x8 bf = *(const f16x8*)(Wf + boff);
#pragma unroll
        for (int mt = 0; mt < 2; ++mt)
          acc[mt][nt] = __builtin_amdgcn_mfma_f32_16x16x32_f16(af[mt], bf, acc[mt][nt], 0, 0, 0);
      }
    }
  }
  // epilogue: D[row=(lane>>4)*4+i][col=lane&15]
#pragma unroll
  for (int mt = 0; mt < 2; ++mt) {
#pragma unroll
    for (int nt = 0; nt < 6; ++nt) {
      int n = (wn + nt) * 16 + c;
      int mat = n >> 7, col = n & 127;
#pragma unroll
      for (int i = 0; i < 4; ++i) {
        int row = m0 + mt * 16 + g * 4 + i;
        _Float16 hv = (_Float16)acc[mt][nt][i];
        if (mat == 0)      qo[(size_t)row * 128 + col] = hv;
        else if (mat == 1) ko[(size_t)row * 128 + col] = hv;
        else               vTo[(size_t)col * 16384 + row] = hv;
      }
    }
  }
}

// ---- flash attention partials, transposed-S formulation ----
// S^T = K·Q^T : D[row = kv-local][col = q-local], softmax per q-col in-lane.
__global__ __launch_bounds__(256, 3) void attn_part(
    const _Float16* __restrict__ qg, const _Float16* __restrict__ kg,
    const _Float16* __restrict__ vT,
    float* __restrict__ Op, float* __restrict__ Ml) {
  __shared__ __align__(16) _Float16 Ks[64 * 136];   // [kv][h] pad 136
  __shared__ __align__(16) _Float16 Vt[128 * 72];   // [h][kv] pad 72
  __shared__ __align__(16) _Float16 Ps[4][16 * 72]; // per-wave P [q][kv] pad 72
  int tid = threadIdx.x;
  int wave = tid >> 6, lane = tid & 63;
  int g = lane >> 4, c = lane & 15;
  int u = blockIdx.x;
  int b = u / 160, t = u % 160;
  int qt, ch;
  if (t < 16)      { qt = t;                 ch = 0; }
  else if (t < 48) { qt = 16 + (t - 16) / 2; ch = (t - 16) % 2; }
  else if (t < 96) { qt = 32 + (t - 48) / 3; ch = (t - 48) % 3; }
  else             { qt = 48 + (t - 96) / 4; ch = (t - 96) % 4; }
  int q0 = qt * 64;
  int jbeg = ch * 16, jend = min(jbeg + 16, qt + 1);
  size_t base = (size_t)b * 4096 * 128;

  // Q as B-frags: B[k][n]: n = c -> q-row (q0 + wave*16 + c), k = kc*32+g*8+j
  f16x8 qf[4];
#pragma unroll
  for (int kc = 0; kc < 4; ++kc)
    qf[kc] = *(const f16x8*)(qg + base + (size_t)(q0 + wave * 16 + c) * 128 + kc * 32 + g * 8);

  const f32x4 fz = {0.f, 0.f, 0.f, 0.f};
  f32x4 o[8];
#pragma unroll
  for (int hh = 0; hh < 8; ++hh) o[hh] = fz;
  float mrow = -1e30f, lrow = 0.f;   // col-world: this lane's q = wave*16 + c

  int kr = tid >> 4, kc8 = tid & 15;  // K staging: 16 rows x 16 8-elem chunks
  int vh = tid >> 3, vt8 = tid & 7;   // V staging: 32 h-rows x 8 chunks
  uint4 rk[4], rv[4];
#pragma unroll
  for (int z = 0; z < 4; ++z) {
    rk[z] = *(const uint4*)(kg + base + (size_t)(jbeg * 64 + z * 16 + kr) * 128 + kc8 * 8);
    rv[z] = *(const uint4*)(vT + (size_t)(z * 32 + vh) * 16384 + b * 4096 + jbeg * 64 + vt8 * 8);
  }

  for (int j = jbeg; j < jend; ++j) {
    __syncthreads();
#pragma unroll
    for (int z = 0; z < 4; ++z) {
      *(uint4*)(Ks + (z * 16 + kr) * 136 + kc8 * 8) = rk[z];
      *(uint4*)(Vt + (z * 32 + vh) * 72 + vt8 * 8) = rv[z];
    }
    if (j + 1 < jend) {
#pragma unroll
      for (int z = 0; z < 4; ++z) {
        rk[z] = *(const uint4*)(kg + base + (size_t)((j + 1) * 64 + z * 16 + kr) * 128 + kc8 * 8);
        rv[z] = *(const uint4*)(vT + (size_t)(z * 32 + vh) * 16384 + b * 4096 + (j + 1) * 64 + vt8 * 8);
      }
    }
    __syncthreads();

    // S^T tiles: s[mt] covers kv rows mt*16.., q cols = this wave's 16 q
    f32x4 s[4];
#pragma unroll
    for (int mt = 0; mt < 4; ++mt) s[mt] = fz;
#pragma unroll
    for (int kc = 0; kc < 4; ++kc) {
#pragma unroll
      for (int mt = 0; mt < 4; ++mt) {
        f16x8 kf = *(const f16x8*)(Ks + (mt * 16 + c) * 136 + kc * 32 + g * 8);
        s[mt] = __builtin_amdgcn_mfma_f32_16x16x32_f16(kf, qf[kc], s[mt], 0, 0, 0);
      }
    }
    // scale + causal mask + per-lane softmax (lane's q-col = wave*16 + c)
    bool diag = (j == qt);
    float tmax = -1e30f;
#pragma unroll
    for (int mt = 0; mt < 4; ++mt)
#pragma unroll
      for (int i = 0; i < 4; ++i) {
        float v = s[mt][i] * SCALE;
        if (diag && (mt * 16 + g * 4 + i) > (wave * 16 + c)) v = -1e30f;
        s[mt][i] = v;
        tmax = fmaxf(tmax, v);
      }
    tmax = fmaxf(tmax, __shfl_xor(tmax, 16, 64));
    tmax = fmaxf(tmax, __shfl_xor(tmax, 32, 64));
    float mnew = fmaxf(mrow, tmax);
    float alpha = __builtin_amdgcn_exp2f((mrow - mnew) * LOG2E);
    float p[4][4];
    float rsum = 0.f;
#pragma unroll
    for (int mt = 0; mt < 4; ++mt)
#pragma unroll
      for (int i = 0; i < 4; ++i) {
        float e = __builtin_amdgcn_exp2f((s[mt][i] - mnew) * LOG2E);
        p[mt][i] = e;
        rsum += e;
      }
    rsum += __shfl_xor(rsum, 16, 64);
    rsum += __shfl_xor(rsum, 32, 64);
    lrow = lrow * alpha + rsum;
    mrow = mnew;
    // alpha from col-world (q=c) to row-world (q = g*4+i): src lane = (lane&48) + (lane&48)>>2 + i
    int srcb = (lane & 48) + ((lane & 48) >> 2);
    float ar[4];
#pragma unroll
    for (int i = 0; i < 4; ++i) ar[i] = __shfl(alpha, srcb + i, 64);
#pragma unroll
    for (int hh = 0; hh < 8; ++hh)
#pragma unroll
      for (int i = 0; i < 4; ++i) o[hh][i] *= ar[i];
    // P^T regs -> Ps[q][kv] packed b64: lane(g,c) reg(mt,i) is (q=c, kv=mt*16+g*4+i)
#pragma unroll
    for (int mt = 0; mt < 4; ++mt) {
      f16x4 pk;
#pragma unroll
      for (int i = 0; i < 4; ++i) pk[i] = (_Float16)p[mt][i];
      *(f16x4*)(&Ps[wave][0] + c * 72 + mt * 16 + g * 4) = pk;
    }
    // O += P V  (A = P[q][kv], B = V[kv][h] via Vt[h][kv] reads)
#pragma unroll
    for (int kc = 0; kc < 2; ++kc) {
      f16x8 pf = *(const f16x8*)(&Ps[wave][0] + c * 72 + kc * 32 + g * 8);
#pragma unroll
      for (int hh = 0; hh < 8; ++hh) {
        f16x8 vf = *(const f16x8*)(Vt + (hh * 16 + c) * 72 + kc * 32 + g * 8);
        o[hh] = __builtin_amdgcn_mfma_f32_16x16x32_f16(pf, vf, o[hh], 0, 0, 0);
      }
    }
  }
  // write unnormalized partial O (row-world) + (m,l) (col-world rows)
#pragma unroll
  for (int hh = 0; hh < 8; ++hh)
#pragma unroll
    for (int i = 0; i < 4; ++i) {
      int row = wave * 16 + g * 4 + i;
      Op[(size_t)u * 8192 + row * 128 + hh * 16 + c] = o[hh][i];
    }
  if (lane < 16) {
    int row = wave * 16 + lane;
    Ml[(size_t)u * 128 + row * 2]     = mrow;
    Ml[(size_t)u * 128 + row * 2 + 1] = lrow;
  }
}

// ---- merge partials -> out ----
__global__ __launch_bounds__(256) void attn_merge(const float* __restrict__ Op,
    const float* __restrict__ Ml, float* __restrict__ out) {
  int bq = blockIdx.x;
  int b = bq >> 6, qt = bq & 63;
  int nch = qt / 16 + 1;
  int bb = (qt < 16) ? qt : (qt < 32) ? 16 + 2 * (qt - 16)
           : (qt < 48) ? 48 + 3 * (qt - 32) : 96 + 4 * (qt - 48);
  int u0 = b * 160 + bb;
  __shared__ float w[4][64];
  int tid = threadIdx.x;
  if (tid < 64) {
    float m[4], l[4];
    float M = -1e30f;
    for (int uu = 0; uu < nch; ++uu) {
      m[uu] = Ml[(size_t)(u0 + uu) * 128 + tid * 2];
      l[uu] = Ml[(size_t)(u0 + uu) * 128 + tid * 2 + 1];
      M = fmaxf(M, m[uu]);
    }
    float L = 0.f;
    for (int uu = 0; uu < nch; ++uu) {
      float e = __builtin_amdgcn_exp2f((m[uu] - M) * LOG2E);
      w[uu][tid] = e;
      L += l[uu] * e;
    }
    float iL = 1.0f / L;
    for (int uu = 0; uu < nch; ++uu) w[uu][tid] *= iL;
  }
  __syncthreads();
  for (int it = 0; it < 32; ++it) {
    int idx = it * 256 + tid;
    int row = idx >> 7;
    float acc = 0.f;
    for (int uu = 0; uu < nch; ++uu)
      acc += w[uu][row] * Op[(size_t)(u0 + uu) * 8192 + idx];
    out[(size_t)b * 4096 * 128 + (size_t)qt * 8192 + idx] = acc;
  }
}

extern "C" void kernel_launch(void* const* d_in, const int* in_sizes, int n_in,
                              void* d_out, int out_size, void* d_ws, size_t ws_size,
                              hipStream_t stream) {
  const float* x  = (const float*)d_in[0];
  const float* Wq = (const float*)d_in[1];
  const float* Wk = (const float*)d_in[2];
  const float* Wv = (const float*)d_in[3];
  const size_t NTOK = (size_t)16384 * 128;
  _Float16* q  = (_Float16*)d_ws;
  _Float16* k  = q + NTOK;
  _Float16* vT = k + NTOK;
  _Float16* Wf = vT + NTOK;                    // 786432 fp16
  float* Op = (float*)(Wf + (size_t)786432);   // 640 * 8192 f32
  float* Ml = Op + (size_t)640 * 8192;         // 640 * 128 f32
  prep_wf<<<384, 256, 0, stream>>>(Wq, Wk, Wv, Wf);
  proj<<<512, 256, 0, stream>>>(x, Wf, q, k, vT);
  attn_part<<<640, 256, 0, stream>>>(q, k, vT, Op, Ml);
  attn_merge<<<256, 256, 0, stream>>>(Op, Ml, (float*)d_out);
}

// Round 5
// 397.830 us; speedup vs baseline: 1.4989x; 1.1122x over previous
//
#include <hip/hip_runtime.h>

#define LOG2E 1.4426950408889634f
#define SCALE 0.6830207f   // 2048^(-0.05)

typedef __attribute__((ext_vector_type(8))) _Float16 f16x8;
typedef __attribute__((ext_vector_type(4))) _Float16 f16x4;
typedef __attribute__((ext_vector_type(4))) float f32x4;

// Workgroup barrier WITHOUT the vmcnt(0) drain __syncthreads carries.
// LDS visibility needs lgkmcnt(0); outstanding global loads stay in flight.
__device__ __forceinline__ void wg_barrier() {
  asm volatile("s_waitcnt lgkmcnt(0)\n\ts_barrier" ::: "memory");
}

// ---- prep: W (3x [2048][128] fp32) -> fp16 MFMA B-frag layout ----
// Wf[kc][nt][lane][j] = W[k = kc*32 + (lane>>4)*8 + j][n = nt*16 + (lane&15)]
__global__ __launch_bounds__(256) void prep_wf(const float* __restrict__ Wq,
    const float* __restrict__ Wk, const float* __restrict__ Wv,
    _Float16* __restrict__ Wf) {
  int t = blockIdx.x * 256 + threadIdx.x;   // 0..98303
  int lane = t & 63;
  int nt = (t >> 6) % 24;
  int kc = t / (64 * 24);
  int g = lane >> 4, c = lane & 15;
  int n = nt * 16 + c;
  const float* W = (n < 128) ? Wq : ((n < 256) ? Wk : Wv);
  int nn = n & 127;
  f16x8 o;
#pragma unroll
  for (int j = 0; j < 8; ++j) {
    int k = kc * 32 + g * 8 + j;
    o[j] = (_Float16)W[k * 128 + nn];
  }
  *(f16x8*)(Wf + (size_t)t * 8) = o;
}

// ---- projection: BM=32, BK=64, fp16; single-barrier double-buffered LDS,
//      distance-3 register prefetch of x, B-frags direct from global/L2 ----
__global__ __launch_bounds__(256, 2) void proj(const float* __restrict__ x,
    const _Float16* __restrict__ Wf,
    _Float16* __restrict__ qo, _Float16* __restrict__ ko,
    _Float16* __restrict__ vTo) {
  __shared__ __align__(16) _Float16 As[2][32 * 72];   // [buf][m][k0..63] pad 72
  int tid = threadIdx.x;
  int wave = tid >> 6, lane = tid & 63;
  int g = lane >> 4, c = lane & 15;
  int m0 = blockIdx.x * 32;
  int wn = wave * 6;
  const f32x4 fz = {0.f, 0.f, 0.f, 0.f};
  f32x4 acc[2][6];
#pragma unroll
  for (int a = 0; a < 2; ++a)
#pragma unroll
    for (int q = 0; q < 6; ++q) acc[a][q] = fz;

  int r = tid >> 3, c4 = tid & 7;  // 32 rows x 8 chunks of 8 floats
  const float* xp = x + (size_t)(m0 + r) * 2048 + c4 * 8;
  float4 pa[4], pb[4];
#pragma unroll
  for (int z = 0; z < 4; ++z) {
    pa[z] = *(const float4*)(xp + z * 64);
    pb[z] = *(const float4*)(xp + z * 64 + 4);
  }
  {
    f16x8 h8;
    h8[0] = (_Float16)pa[0].x; h8[1] = (_Float16)pa[0].y;
    h8[2] = (_Float16)pa[0].z; h8[3] = (_Float16)pa[0].w;
    h8[4] = (_Float16)pb[0].x; h8[5] = (_Float16)pb[0].y;
    h8[6] = (_Float16)pb[0].z; h8[7] = (_Float16)pb[0].w;
    *(f16x8*)(&As[0][0] + r * 72 + c4 * 8) = h8;
  }
  wg_barrier();

#pragma unroll 4
  for (int kb = 0; kb < 32; ++kb) {
    if (kb + 1 < 32) {
      int s = (kb + 1) & 3;
      f16x8 h8;
      h8[0] = (_Float16)pa[s].x; h8[1] = (_Float16)pa[s].y;
      h8[2] = (_Float16)pa[s].z; h8[3] = (_Float16)pa[s].w;
      h8[4] = (_Float16)pb[s].x; h8[5] = (_Float16)pb[s].y;
      h8[6] = (_Float16)pb[s].z; h8[7] = (_Float16)pb[s].w;
      *(f16x8*)(&As[(kb + 1) & 1][0] + r * 72 + c4 * 8) = h8;
    }
    if (kb + 4 < 32) {
      pa[kb & 3] = *(const float4*)(xp + (kb + 4) * 64);
      pb[kb & 3] = *(const float4*)(xp + (kb + 4) * 64 + 4);
    }
    const _Float16* Ab = &As[kb & 1][0];
#pragma unroll
    for (int kcl = 0; kcl < 2; ++kcl) {
      f16x8 af[2];
#pragma unroll
      for (int mt = 0; mt < 2; ++mt)
        af[mt] = *(const f16x8*)(Ab + (mt * 16 + c) * 72 + kcl * 32 + g * 8);
#pragma unroll
      for (int nt = 0; nt < 6; ++nt) {
        size_t boff = ((size_t)((kb * 2 + kcl) * 24 + wn + nt) * 64 + lane) * 8;
        f16x8 bf = *(const f16x8*)(Wf + boff);
#pragma unroll
        for (int mt = 0; mt < 2; ++mt)
          acc[mt][nt] = __builtin_amdgcn_mfma_f32_16x16x32_f16(af[mt], bf, acc[mt][nt], 0, 0, 0);
      }
    }
    wg_barrier();
  }
  // epilogue: D[row=(lane>>4)*4+i][col=lane&15]
#pragma unroll
  for (int mt = 0; mt < 2; ++mt) {
#pragma unroll
    for (int nt = 0; nt < 6; ++nt) {
      int n = (wn + nt) * 16 + c;
      int mat = n >> 7, col = n & 127;
#pragma unroll
      for (int i = 0; i < 4; ++i) {
        int row = m0 + mt * 16 + g * 4 + i;
        _Float16 hv = (_Float16)acc[mt][nt][i];
        if (mat == 0)      qo[(size_t)row * 128 + col] = hv;
        else if (mat == 1) ko[(size_t)row * 128 + col] = hv;
        else               vTo[(size_t)col * 16384 + row] = hv;
      }
    }
  }
}

// ---- flash attention partials, transposed-S formulation ----
__global__ __launch_bounds__(256, 3) void attn_part(
    const _Float16* __restrict__ qg, const _Float16* __restrict__ kg,
    const _Float16* __restrict__ vT,
    float* __restrict__ Op, float* __restrict__ Ml) {
  __shared__ __align__(16) _Float16 Ks[64 * 136];   // [kv][h] pad 136
  __shared__ __align__(16) _Float16 Vt[128 * 72];   // [h][kv] pad 72
  __shared__ __align__(16) _Float16 Ps[4][16 * 72]; // per-wave P [q][kv] pad 72
  int tid = threadIdx.x;
  int wave = tid >> 6, lane = tid & 63;
  int g = lane >> 4, c = lane & 15;
  int u = blockIdx.x;
  int b = u / 160, t = u % 160;
  int qt, ch;
  if (t < 16)      { qt = t;                 ch = 0; }
  else if (t < 48) { qt = 16 + (t - 16) / 2; ch = (t - 16) % 2; }
  else if (t < 96) { qt = 32 + (t - 48) / 3; ch = (t - 48) % 3; }
  else             { qt = 48 + (t - 96) / 4; ch = (t - 96) % 4; }
  int q0 = qt * 64;
  int jbeg = ch * 16, jend = min(jbeg + 16, qt + 1);
  size_t base = (size_t)b * 4096 * 128;

  f16x8 qf[4];
#pragma unroll
  for (int kc = 0; kc < 4; ++kc)
    qf[kc] = *(const f16x8*)(qg + base + (size_t)(q0 + wave * 16 + c) * 128 + kc * 32 + g * 8);

  const f32x4 fz = {0.f, 0.f, 0.f, 0.f};
  f32x4 o[8];
#pragma unroll
  for (int hh = 0; hh < 8; ++hh) o[hh] = fz;
  float mrow = -1e30f, lrow = 0.f;   // col-world: this lane's q = wave*16 + c

  int kr = tid >> 4, kc8 = tid & 15;  // K staging: 16 rows x 16 8-elem chunks
  int vh = tid >> 3, vt8 = tid & 7;   // V staging: 32 h-rows x 8 chunks
  uint4 rk[4], rv[4];
#pragma unroll
  for (int z = 0; z < 4; ++z) {
    rk[z] = *(const uint4*)(kg + base + (size_t)(jbeg * 64 + z * 16 + kr) * 128 + kc8 * 8);
    rv[z] = *(const uint4*)(vT + (size_t)(z * 32 + vh) * 16384 + b * 4096 + jbeg * 64 + vt8 * 8);
  }

  for (int j = jbeg; j < jend; ++j) {
    wg_barrier();   // all waves done reading Ks/Vt from previous iter
#pragma unroll
    for (int z = 0; z < 4; ++z) {
      *(uint4*)(Ks + (z * 16 + kr) * 136 + kc8 * 8) = rk[z];
      *(uint4*)(Vt + (z * 32 + vh) * 72 + vt8 * 8) = rv[z];
    }
    if (j + 1 < jend) {
#pragma unroll
      for (int z = 0; z < 4; ++z) {
        rk[z] = *(const uint4*)(kg + base + (size_t)((j + 1) * 64 + z * 16 + kr) * 128 + kc8 * 8);
        rv[z] = *(const uint4*)(vT + (size_t)(z * 32 + vh) * 16384 + b * 4096 + (j + 1) * 64 + vt8 * 8);
      }
    }
    wg_barrier();   // staging visible

    f32x4 s[4];
#pragma unroll
    for (int mt = 0; mt < 4; ++mt) s[mt] = fz;
#pragma unroll
    for (int kc = 0; kc < 4; ++kc) {
#pragma unroll
      for (int mt = 0; mt < 4; ++mt) {
        f16x8 kf = *(const f16x8*)(Ks + (mt * 16 + c) * 136 + kc * 32 + g * 8);
        s[mt] = __builtin_amdgcn_mfma_f32_16x16x32_f16(kf, qf[kc], s[mt], 0, 0, 0);
      }
    }
    bool diag = (j == qt);
    float tmax = -1e30f;
#pragma unroll
    for (int mt = 0; mt < 4; ++mt)
#pragma unroll
      for (int i = 0; i < 4; ++i) {
        float v = s[mt][i] * SCALE;
        if (diag && (mt * 16 + g * 4 + i) > (wave * 16 + c)) v = -1e30f;
        s[mt][i] = v;
        tmax = fmaxf(tmax, v);
      }
    tmax = fmaxf(tmax, __shfl_xor(tmax, 16, 64));
    tmax = fmaxf(tmax, __shfl_xor(tmax, 32, 64));
    float mnew = fmaxf(mrow, tmax);
    float alpha = __builtin_amdgcn_exp2f((mrow - mnew) * LOG2E);
    float p[4][4];
    float rsum = 0.f;
#pragma unroll
    for (int mt = 0; mt < 4; ++mt)
#pragma unroll
      for (int i = 0; i < 4; ++i) {
        float e = __builtin_amdgcn_exp2f((s[mt][i] - mnew) * LOG2E);
        p[mt][i] = e;
        rsum += e;
      }
    rsum += __shfl_xor(rsum, 16, 64);
    rsum += __shfl_xor(rsum, 32, 64);
    lrow = lrow * alpha + rsum;
    mrow = mnew;
    int srcb = (lane & 48) + ((lane & 48) >> 2);
    float ar[4];
#pragma unroll
    for (int i = 0; i < 4; ++i) ar[i] = __shfl(alpha, srcb + i, 64);
#pragma unroll
    for (int hh = 0; hh < 8; ++hh)
#pragma unroll
      for (int i = 0; i < 4; ++i) o[hh][i] *= ar[i];
#pragma unroll
    for (int mt = 0; mt < 4; ++mt) {
      f16x4 pk;
#pragma unroll
      for (int i = 0; i < 4; ++i) pk[i] = (_Float16)p[mt][i];
      *(f16x4*)(&Ps[wave][0] + c * 72 + mt * 16 + g * 4) = pk;
    }
#pragma unroll
    for (int kc = 0; kc < 2; ++kc) {
      f16x8 pf = *(const f16x8*)(&Ps[wave][0] + c * 72 + kc * 32 + g * 8);
#pragma unroll
      for (int hh = 0; hh < 8; ++hh) {
        f16x8 vf = *(const f16x8*)(Vt + (hh * 16 + c) * 72 + kc * 32 + g * 8);
        o[hh] = __builtin_amdgcn_mfma_f32_16x16x32_f16(pf, vf, o[hh], 0, 0, 0);
      }
    }
  }
#pragma unroll
  for (int hh = 0; hh < 8; ++hh)
#pragma unroll
    for (int i = 0; i < 4; ++i) {
      int row = wave * 16 + g * 4 + i;
      Op[(size_t)u * 8192 + row * 128 + hh * 16 + c] = o[hh][i];
    }
  if (lane < 16) {
    int row = wave * 16 + lane;
    Ml[(size_t)u * 128 + row * 2]     = mrow;
    Ml[(size_t)u * 128 + row * 2 + 1] = lrow;
  }
}

// ---- merge partials -> out ----
__global__ __launch_bounds__(256) void attn_merge(const float* __restrict__ Op,
    const float* __restrict__ Ml, float* __restrict__ out) {
  int bq = blockIdx.x;
  int b = bq >> 6, qt = bq & 63;
  int nch = qt / 16 + 1;
  int bb = (qt < 16) ? qt : (qt < 32) ? 16 + 2 * (qt - 16)
           : (qt < 48) ? 48 + 3 * (qt - 32) : 96 + 4 * (qt - 48);
  int u0 = b * 160 + bb;
  __shared__ float w[4][64];
  int tid = threadIdx.x;
  if (tid < 64) {
    float m[4], l[4];
    float M = -1e30f;
    for (int uu = 0; uu < nch; ++uu) {
      m[uu] = Ml[(size_t)(u0 + uu) * 128 + tid * 2];
      l[uu] = Ml[(size_t)(u0 + uu) * 128 + tid * 2 + 1];
      M = fmaxf(M, m[uu]);
    }
    float L = 0.f;
    for (int uu = 0; uu < nch; ++uu) {
      float e = __builtin_amdgcn_exp2f((m[uu] - M) * LOG2E);
      w[uu][tid] = e;
      L += l[uu] * e;
    }
    float iL = 1.0f / L;
    for (int uu = 0; uu < nch; ++uu) w[uu][tid] *= iL;
  }
  __syncthreads();
  for (int it = 0; it < 32; ++it) {
    int idx = it * 256 + tid;
    int row = idx >> 7;
    float acc = 0.f;
    for (int uu = 0; uu < nch; ++uu)
      acc += w[uu][row] * Op[(size_t)(u0 + uu) * 8192 + idx];
    out[(size_t)b * 4096 * 128 + (size_t)qt * 8192 + idx] = acc;
  }
}

extern "C" void kernel_launch(void* const* d_in, const int* in_sizes, int n_in,
                              void* d_out, int out_size, void* d_ws, size_t ws_size,
                              hipStream_t stream) {
  const float* x  = (const float*)d_in[0];
  const float* Wq = (const float*)d_in[1];
  const float* Wk = (const float*)d_in[2];
  const float* Wv = (const float*)d_in[3];
  const size_t NTOK = (size_t)16384 * 128;
  _Float16* q  = (_Float16*)d_ws;
  _Float16* k  = q + NTOK;
  _Float16* vT = k + NTOK;
  _Float16* Wf = vT + NTOK;                    // 786432 fp16
  float* Op = (float*)(Wf + (size_t)786432);   // 640 * 8192 f32
  float* Ml = Op + (size_t)640 * 8192;         // 640 * 128 f32
  prep_wf<<<384, 256, 0, stream>>>(Wq, Wk, Wv, Wf);
  proj<<<512, 256, 0, stream>>>(x, Wf, q, k, vT);
  attn_part<<<640, 256, 0, stream>>>(q, k, vT, Op, Ml);
  attn_merge<<<256, 256, 0, stream>>>(Op, Ml, (float*)d_out);
}